// Round 14
// baseline (94.589 us; speedup 1.0000x reference)
//
#include <hip/hip_runtime.h>
#include <math.h>

#define BB 64
#define NN 4096
#define DD 128
#define HH 256
#define PPB 32                  // wave-partials per batch
#define PSTRIDE 132             // per-wave partial: 128 acc + m + z (+pad)

typedef __attribute__((ext_vector_type(8))) _Float16 f16x8;
typedef __attribute__((ext_vector_type(4))) float f32x4;

static __device__ __forceinline__ void gload_lds16(const void* g, void* l) {
    __builtin_amdgcn_global_load_lds(
        (const __attribute__((address_space(1))) unsigned int*)g,
        (__attribute__((address_space(3))) unsigned int*)l, 16, 0, 0);
}

// ---------------------------------------------------------------------------
// k_prep: W1 [128][256] fp32 -> Bws fp16, transposed per 16-col chunk,
// XOR-swizzled exactly as it will sit in LDS (linear global_load_lds copy).
// chunk region = 4096 B; elem (cl, k) at ((cl<<8)+(k<<1)) ^ ((cl&7)<<4).
// ---------------------------------------------------------------------------
__global__ __launch_bounds__(256) void k_prep(const float* __restrict__ W1,
                                              char* __restrict__ Bws) {
    const int k = blockIdx.x;       // 0..127
    const int c = threadIdx.x;      // 0..255
    const _Float16 h = (_Float16)W1[k * HH + c];
    const int chunk = c >> 4, cl = c & 15;
    const int off = ((cl << 8) + (k << 1)) ^ ((cl & 7) << 4);
    *(_Float16*)(Bws + chunk * 4096 + off) = h;
}

// ---------------------------------------------------------------------------
// k_fused: barrier-free per-wave flash loop.
//   Block = (batch, slice of 512 rows); 4 waves; B (W1t fp16, 64 KiB) staged
//   once, ONE barrier. Each wave independently processes 2 tiles of 64 rows:
//   scores via MFMA -> intra-wave shuffle reduce -> ONLINE softmax (running
//   m,z + rescaled 32-reg weighted acc) -> weighted acc from the same A
//   fragments via shuffle-transpose. No LDS / no barriers in the loop.
// HARD-WON RULES: launch_bounds min-waves stays 2 (r8/r11: >=4 -> 64-VGPR
// budget -> massive spill). No runtime-indexed register arrays (r7).
// ---------------------------------------------------------------------------
__global__ __launch_bounds__(256, 2) void k_fused(const float* __restrict__ feats,
                                                  const char* __restrict__ Bws,
                                                  const float* __restrict__ b1,
                                                  const float* __restrict__ W2,
                                                  float* __restrict__ parts) {
    __shared__ char Bl[65536];      // 16 chunks x 16 cols x 128 k, fp16 swizzled

    const int tid   = threadIdx.x;
    const int lane  = tid & 63;
    const int wv    = tid >> 6;     // 0..3
    const int batch = blockIdx.x >> 3;
    const int slice = blockIdx.x & 7;
    const int rl    = lane & 15;    // A row within 16-tile / B col within chunk
    const int q     = lane >> 4;    // k-quarter (8 elems per K=32 step)

    // ---- stage all of B: 64 KiB = 16 iters x 256 threads x 16 B (linear)
    #pragma unroll
    for (int it = 0; it < 16; ++it)
        gload_lds16(Bws + it * 4096 + tid * 16, Bl + it * 4096 + tid * 16);
    __syncthreads();                // the ONLY barrier

    const int brow = rl << 8;
    const int bswz = (rl & 7) << 4;
    const int bq   = q << 4;

    float m = -1e30f, z = 0.f;
    float acc[4][8] = {{0,0,0,0,0,0,0,0},{0,0,0,0,0,0,0,0},
                       {0,0,0,0,0,0,0,0},{0,0,0,0,0,0,0,0}};
    const float* fb = feats + ((size_t)batch * NN + slice * 512 + wv * 128) * DD;

    for (int tile = 0; tile < 2; ++tile) {
        // ---- A fragments for 64 rows: lane (q,rl) holds rows t*16+rl,
        // k = kk*32 + q*8 + e
        f16x8 af[4][4];
        #pragma unroll
        for (int t = 0; t < 4; ++t) {
            const float* rp = fb + (tile * 64 + t * 16 + rl) * DD + q * 8;
            #pragma unroll
            for (int kk = 0; kk < 4; ++kk) {
                float4 v0 = *(const float4*)(rp + kk * 32);
                float4 v1 = *(const float4*)(rp + kk * 32 + 4);
                f16x8 a;
                a[0] = (_Float16)v0.x; a[1] = (_Float16)v0.y;
                a[2] = (_Float16)v0.z; a[3] = (_Float16)v0.w;
                a[4] = (_Float16)v1.x; a[5] = (_Float16)v1.y;
                a[6] = (_Float16)v1.z; a[7] = (_Float16)v1.w;
                af[t][kk] = a;
            }
        }

        // ---- scores for the 64 rows
        float sp[4][4] = {{0,0,0,0},{0,0,0,0},{0,0,0,0},{0,0,0,0}};
        #pragma unroll
        for (int chunk = 0; chunk < 16; ++chunk) {
            const float bbv = b1[chunk * 16 + rl];
            const float ww  = W2[chunk * 16 + rl];
            const char* cb = Bl + chunk * 4096;
            f32x4 a0 = {0,0,0,0}, a1 = {0,0,0,0}, a2 = {0,0,0,0}, a3 = {0,0,0,0};
            #pragma unroll
            for (int kk = 0; kk < 4; ++kk) {
                f16x8 bf = *(const f16x8*)(cb + ((brow + (kk << 6) + bq) ^ bswz));
                a0 = __builtin_amdgcn_mfma_f32_16x16x32_f16(af[0][kk], bf, a0, 0, 0, 0);
                a1 = __builtin_amdgcn_mfma_f32_16x16x32_f16(af[1][kk], bf, a1, 0, 0, 0);
                a2 = __builtin_amdgcn_mfma_f32_16x16x32_f16(af[2][kk], bf, a2, 0, 0, 0);
                a3 = __builtin_amdgcn_mfma_f32_16x16x32_f16(af[3][kk], bf, a3, 0, 0, 0);
            }
            // fold relu + W2; D layout: col = rl, row = q*4 + j (in tile t)
            #pragma unroll
            for (int j = 0; j < 4; ++j) {
                sp[0][j] += fmaxf(a0[j] + bbv, 0.f) * ww;
                sp[1][j] += fmaxf(a1[j] + bbv, 0.f) * ww;
                sp[2][j] += fmaxf(a2[j] + bbv, 0.f) * ww;
                sp[3][j] += fmaxf(a3[j] + bbv, 0.f) * ww;
            }
        }
        // reduce over the 16 rl-lanes (h-cols); sp then row-score at (q,j)
        #pragma unroll
        for (int o = 1; o < 16; o <<= 1)
            #pragma unroll
            for (int t = 0; t < 4; ++t)
                #pragma unroll
                for (int j = 0; j < 4; ++j)
                    sp[t][j] += __shfl_xor(sp[t][j], o);

        // ---- online softmax update (per wave, 64 rows)
        float mt = sp[0][0];
        #pragma unroll
        for (int t = 0; t < 4; ++t)
            #pragma unroll
            for (int j = 0; j < 4; ++j)
                mt = fmaxf(mt, sp[t][j]);
        mt = fmaxf(mt, __shfl_xor(mt, 16));
        mt = fmaxf(mt, __shfl_xor(mt, 32));
        const float mnew  = fmaxf(m, mt);
        const float scale = expf(m - mnew);       // first tile: exp(-inf)=0
        float ze = 0.f;
        #pragma unroll
        for (int t = 0; t < 4; ++t)
            #pragma unroll
            for (int j = 0; j < 4; ++j) {
                sp[t][j] = expf(sp[t][j] - mnew);
                ze += sp[t][j];
            }
        ze += __shfl_xor(ze, 16);
        ze += __shfl_xor(ze, 32);
        z = z * scale + ze;
        m = mnew;
        #pragma unroll
        for (int kk = 0; kk < 4; ++kk)
            #pragma unroll
            for (int e8 = 0; e8 < 8; ++e8)
                acc[kk][e8] *= scale;

        // ---- weighted acc += e(row rl of sub-tile t) * af[t]
        // e for row t*16+rl lives at lane (q'=rl>>2, j'=rl&3): shuffle-
        // transpose with static register indices (rule #20).
        const int srcl = (rl >> 2) << 4;
        const int jsel = rl & 3;
        #pragma unroll
        for (int t = 0; t < 4; ++t) {
            const float c0 = __shfl(sp[t][0], srcl);
            const float c1 = __shfl(sp[t][1], srcl);
            const float c2 = __shfl(sp[t][2], srcl);
            const float c3 = __shfl(sp[t][3], srcl);
            const float et = jsel == 0 ? c0 : jsel == 1 ? c1 : jsel == 2 ? c2 : c3;
            #pragma unroll
            for (int kk = 0; kk < 4; ++kk)
                #pragma unroll
                for (int e8 = 0; e8 < 8; ++e8)
                    acc[kk][e8] = fmaf(et, (float)af[t][kk][e8], acc[kk][e8]);
        }
    }

    // ---- fold the 16 rl-lanes' k-slice partials; write wave partial
    #pragma unroll
    for (int o = 1; o < 16; o <<= 1)
        #pragma unroll
        for (int kk = 0; kk < 4; ++kk)
            #pragma unroll
            for (int e8 = 0; e8 < 8; ++e8)
                acc[kk][e8] += __shfl_xor(acc[kk][e8], o);
    const int pbase = (batch * PPB + slice * 4 + wv) * PSTRIDE;
    if (rl == 0) {
        #pragma unroll
        for (int kk = 0; kk < 4; ++kk)
            #pragma unroll
            for (int e8 = 0; e8 < 8; ++e8)
                parts[pbase + kk * 32 + q * 8 + e8] = acc[kk][e8];
    }
    if (lane == 0) {
        parts[pbase + 128] = m;
        parts[pbase + 129] = z;
    }
}

// ---------------------------------------------------------------------------
// k_out: combine 32 wave-partials per batch with exact softmax rescaling.
// ---------------------------------------------------------------------------
__global__ __launch_bounds__(128) void k_out(const float* __restrict__ parts,
                                             float* __restrict__ out) {
    const int b = blockIdx.x;       // 0..63
    const int d = threadIdx.x;      // 0..127
    const float* pb = parts + (size_t)b * PPB * PSTRIDE;
    float M = -1e30f;
    #pragma unroll
    for (int i = 0; i < PPB; ++i) M = fmaxf(M, pb[i * PSTRIDE + 128]);
    float num = 0.f, den = 0.f;
    #pragma unroll
    for (int i = 0; i < PPB; ++i) {
        const float sc = expf(pb[i * PSTRIDE + 128] - M);
        num = fmaf(sc, pb[i * PSTRIDE + d], num);
        den = fmaf(sc, pb[i * PSTRIDE + 129], den);
    }
    out[b * DD + d] = num / den;
}

extern "C" void kernel_launch(void* const* d_in, const int* in_sizes, int n_in,
                              void* d_out, int out_size, void* d_ws, size_t ws_size,
                              hipStream_t stream) {
    const float* feats = (const float*)d_in[0];
    const float* W1    = (const float*)d_in[1];
    const float* b1    = (const float*)d_in[2];
    const float* W2    = (const float*)d_in[3];
    // d_in[4] = b2: constant shift before softmax -> no effect on output.
    float* out = (float*)d_out;

    char*  Bws   = (char*)d_ws;                     // 64 KiB: W1t fp16 swizzled
    float* parts = (float*)((char*)d_ws + 65536);   // 64*32*132 floats

    hipLaunchKernelGGL(k_prep, dim3(DD), dim3(HH), 0, stream, W1, Bws);
    hipLaunchKernelGGL(k_fused, dim3(BB * 8), dim3(256), 0, stream,
                       feats, Bws, b1, W2, parts);
    hipLaunchKernelGGL(k_out, dim3(BB), dim3(128), 0, stream, parts, out);
}